// Round 1
// baseline (720.053 us; speedup 1.0000x reference)
//
#include <hip/hip_runtime.h>

// YOLOv1 loss, fp32, pred/labels (N,30,7,7), scalar out = loss/N.
// Layout: element (n,c,s) at n*1470 + c*49 + s, s = i*7+j in [0,49).

constexpr int CH = 49;            // 7*7 cells per channel plane
constexpr int SAMPLE = 30 * CH;   // 1470 floats per sample
constexpr float OBJ_W   = 5.0f;
constexpr float NOOBJ_W = 0.1f;
constexpr float EPS_IOU = 1e-10f;

__device__ __forceinline__ float iou_f(float acx, float acy, float aw, float ah,
                                       float bcx, float bcy, float bw, float bh) {
    float ax1 = acx - aw * 0.5f, ay1 = acy - ah * 0.5f;
    float ax2 = acx + aw * 0.5f, ay2 = acy + ah * 0.5f;
    float bx1 = bcx - bw * 0.5f, by1 = bcy - bh * 0.5f;
    float bx2 = bcx + bw * 0.5f, by2 = bcy + bh * 0.5f;
    float iw = fmaxf(fminf(ax2, bx2) - fmaxf(ax1, bx1), 0.0f);
    float ih = fmaxf(fminf(ay2, by2) - fmaxf(ay1, by1), 0.0f);
    float inter = iw * ih;
    float area_a = (ax2 - ax1) * (ay2 - ay1);
    float area_b = (bx2 - bx1) * (by2 - by1);
    return inter / (area_a + area_b - inter + EPS_IOU);
}

__global__ __launch_bounds__(256) void yolo_loss_kernel(
    const float* __restrict__ pred, const float* __restrict__ lab,
    float* __restrict__ out, int total_cells, float inv_n) {
    float acc = 0.0f;
    const int stride = gridDim.x * blockDim.x;
    for (int idx = blockIdx.x * blockDim.x + threadIdx.x; idx < total_cells; idx += stride) {
        const int n = idx / CH;             // magic-mul division by 49
        const int s = idx - n * CH;
        const float* p = pred + (size_t)n * SAMPLE + s;
        const float* l = lab  + (size_t)n * SAMPLE + s;

        // box/conf channels (scalar, coalesced within 49-float runs)
        const float p0 = p[0 * CH], p1 = p[1 * CH], p2 = p[2 * CH], p3 = p[3 * CH];
        const float p4 = p[4 * CH];
        const float p5 = p[5 * CH], p6 = p[6 * CH], p7 = p[7 * CH], p8 = p[8 * CH];
        const float p9 = p[9 * CH];
        const float l0 = l[0 * CH], l1 = l[1 * CH], l2 = l[2 * CH], l3 = l[3 * CH];
        const float l4 = l[4 * CH];
        const float l9 = l[9 * CH];
        // labels channels 5..8 are unused by the reference — skipped on purpose.

        const float iou1 = iou_f(p0, p1, p2, p3, l0, l1, l2, l3);
        const float iou2 = iou_f(p5, p6, p7, p8, l0, l1, l2, l3);
        const bool  sel1 = iou1 >= iou2;
        const float objf = (l4 == 1.0f) ? 1.0f : 0.0f;

        // confidence term (only counted when obj)
        const float dconf = sel1 ? (p4 - l4) : (p9 - l9);
        const float conf  = dconf * dconf;

        // no-obj terms
        const float dni       = sel1 ? (p9 - iou1) : (p4 - iou2);
        const float noobj_in  = dni * dni;
        const float noobj_out = p4 * p4 + p9 * p9;

        // bbox term of the selected box vs label box
        const float bx = sel1 ? p0 : p5, by = sel1 ? p1 : p6;
        const float bw = sel1 ? p2 : p7, bh = sel1 ? p3 : p8;
        const float dx = bx - l0, dy = by - l1;
        const float dw = sqrtf(bw) - sqrtf(l2);
        const float dh = sqrtf(bh) - sqrtf(l3);
        const float bbox = dx * dx + dy * dy + dw * dw + dh * dh;

        // classification term, channels 10..29
        float cls = 0.0f;
        #pragma unroll
        for (int c = 10; c < 30; ++c) {
            const float d = p[c * CH] - l[c * CH];
            cls += d * d;
        }

        acc += objf * (conf + OBJ_W * bbox + cls + NOOBJ_W * noobj_in)
             + (1.0f - objf) * (NOOBJ_W * noobj_out);
    }

    // wave64 reduce
    #pragma unroll
    for (int off = 32; off > 0; off >>= 1)
        acc += __shfl_down(acc, off, 64);

    __shared__ float wsum[4];  // 256 threads = 4 waves
    const int lane = threadIdx.x & 63;
    const int wid  = threadIdx.x >> 6;
    if (lane == 0) wsum[wid] = acc;
    __syncthreads();
    if (threadIdx.x == 0) {
        const float bsum = wsum[0] + wsum[1] + wsum[2] + wsum[3];
        atomicAdd(out, bsum * inv_n);
    }
}

extern "C" void kernel_launch(void* const* d_in, const int* in_sizes, int n_in,
                              void* d_out, int out_size, void* d_ws, size_t ws_size,
                              hipStream_t stream) {
    const float* pred = (const float*)d_in[0];
    const float* lab  = (const float*)d_in[1];
    float* out = (float*)d_out;

    const int N = in_sizes[0] / SAMPLE;      // 65536
    const int total_cells = N * CH;          // 3,211,264

    // d_out is poisoned 0xAA before every timed launch — zero it on-stream.
    hipMemsetAsync(out, 0, sizeof(float), stream);

    const int block = 256;
    const int grid = 2048;                   // ~6 cells/thread; 2048 atomics total
    yolo_loss_kernel<<<grid, block, 0, stream>>>(pred, lab, out, total_cells,
                                                 1.0f / (float)N);
}